// Round 3
// baseline (242.794 us; speedup 1.0000x reference)
//
#include <hip/hip_runtime.h>
#include <hip/hip_bf16.h>
#include <stdint.h>

// LoRAExpert: out = ragged_dot(x, W, groups) + scale[a] * ((x @ A[a,e]) @ B[a,e])
// T=8192, D_IN=D_OUT=1024, E=8 (equal groups of 1024), A=4 adapters, R=16.
// Inputs fp32, output fp32 (confirmed round 2).
// Round 3: pre-pack to bf16 in ws -> m97-style async GEMM with global_load_lds.
//   xp  [T][1088]  bf16 : cols 0..1023 = bf16(x); cols 1024..1087 = adapter-
//                         slotted scale*(x@A) (zero outside own adapter slot)
//   Boct[e][136][1024][8] bf16 : oct-interleaved K=1088 B-matrix
//                         (k-octs 0..127 from W[e], 128..135 from lora_B[., e])
// GEMM: out[t][n] = sum_k xp[t][k] * B2[e(t)][k][n], K=1088, branch-free.

#define T_TOK 8192
#define DIN   1024
#define DOUT  1024
#define NE    8
#define NA    4
#define RK    16
#define KEXT  1088      // 1024 + NA*RK
#define NOCT  136       // KEXT/8

typedef __attribute__((ext_vector_type(8))) short short8;
typedef __attribute__((ext_vector_type(4))) float f32x4;

__device__ __forceinline__ ushort f2bf(float f) {
  union { float f; uint32_t i; } v; v.f = f;
  uint32_t x = v.i;
  return (ushort)((x + 0x7fffu + ((x >> 16) & 1u)) >> 16);  // RNE
}

__device__ __forceinline__ void gload_lds16(const void* g, void* l) {
  __builtin_amdgcn_global_load_lds(
      (const __attribute__((address_space(1))) uint32_t*)g,
      (__attribute__((address_space(3))) uint32_t*)l,
      16, 0, 0);
}

// ---- token -> expert map ----
__global__ void k_token_expert(const int* __restrict__ gs, int* __restrict__ tok_exp) {
  int t = blockIdx.x * blockDim.x + threadIdx.x;
  if (t >= T_TOK) return;
  int cum = 0, e = 0;
#pragma unroll
  for (int i = 0; i < NE; ++i) { if (t >= cum) e = i; cum += gs[i]; }
  tok_exp[t] = e;
}

// ---- pack x -> bf16 + fused vprime (adapter-slotted, scaled) ----
// 1 wave per token; 4 tokens per block.
__global__ __launch_bounds__(256) void k_pack_x(
    const float* __restrict__ x, const float* __restrict__ lora_A,
    const float* __restrict__ lora_scaling, const int* __restrict__ adapter_idx,
    const int* __restrict__ tok_exp, ushort* __restrict__ xp) {
  const int lane = threadIdx.x & 63;
  const int t = blockIdx.x * 4 + (threadIdx.x >> 6);
  const int a = adapter_idx[t];
  const int e = tok_exp[t];
  const float* xr = x + (size_t)t * DIN;
  const float* ab = lora_A + (size_t)(a * NE + e) * DIN * RK;

  float acc[RK];
#pragma unroll
  for (int r = 0; r < RK; ++r) acc[r] = 0.f;

#pragma unroll
  for (int i = 0; i < 4; ++i) {
    int k = i * 256 + lane * 4;                 // 4 consecutive k per lane
    float4 xv = *(const float4*)(xr + k);
    ushort4 xb;
    xb.x = f2bf(xv.x); xb.y = f2bf(xv.y); xb.z = f2bf(xv.z); xb.w = f2bf(xv.w);
    *(ushort4*)(xp + (size_t)t * KEXT + k) = xb;
    const float xk[4] = {xv.x, xv.y, xv.z, xv.w};
#pragma unroll
    for (int d = 0; d < 4; ++d) {
      const float* ar = ab + (size_t)(k + d) * RK;   // 64B contiguous per lane
      float4 v0 = *(const float4*)(ar + 0);
      float4 v1 = *(const float4*)(ar + 4);
      float4 v2 = *(const float4*)(ar + 8);
      float4 v3 = *(const float4*)(ar + 12);
      float s = xk[d];
      acc[0]  += s * v0.x; acc[1]  += s * v0.y; acc[2]  += s * v0.z; acc[3]  += s * v0.w;
      acc[4]  += s * v1.x; acc[5]  += s * v1.y; acc[6]  += s * v1.z; acc[7]  += s * v1.w;
      acc[8]  += s * v2.x; acc[9]  += s * v2.y; acc[10] += s * v2.z; acc[11] += s * v2.w;
      acc[12] += s * v3.x; acc[13] += s * v3.y; acc[14] += s * v3.z; acc[15] += s * v3.w;
    }
  }
#pragma unroll
  for (int off = 1; off < 64; off <<= 1) {
#pragma unroll
    for (int r = 0; r < RK; ++r) acc[r] += __shfl_xor(acc[r], off, 64);
  }
  float s = lora_scaling[a];
  int c = lane;                                  // slot column 0..63
  float v = ((c >> 4) == a) ? s * acc[c & 15] : 0.f;
  xp[(size_t)t * KEXT + DIN + c] = f2bf(v);
}

// ---- pack W + lora_B -> oct-interleaved bf16 Boct[e][ko][n][8] ----
// block = 256 threads handles one (e, ko): 8 k-rows x 1024 n.
__global__ __launch_bounds__(256) void k_pack_B(
    const float* __restrict__ weight, const float* __restrict__ lora_B,
    ushort* __restrict__ Boct) {
  const int ko = blockIdx.x;         // 0..135
  const int e  = blockIdx.y;         // 0..7
  const int tid = threadIdx.x;
  const int n4 = tid * 4;            // 4 consecutive n per thread

  float v[8][4];
  if (ko < 128) {
    const float* wb = weight + (size_t)e * DIN * DOUT + (size_t)(ko * 8) * DOUT + n4;
#pragma unroll
    for (int j = 0; j < 8; ++j) {
      float4 q = *(const float4*)(wb + (size_t)j * DOUT);
      v[j][0] = q.x; v[j][1] = q.y; v[j][2] = q.z; v[j][3] = q.w;
    }
  } else {
    int o = ko - 128;
#pragma unroll
    for (int j = 0; j < 8; ++j) {
      int kv = o * 8 + j;            // 0..63
      int a = kv >> 4, r = kv & 15;
      float4 q = *(const float4*)(lora_B + (size_t)((a * NE + e) * RK + r) * DOUT + n4);
      v[j][0] = q.x; v[j][1] = q.y; v[j][2] = q.z; v[j][3] = q.w;
    }
  }
  ushort* dst = Boct + ((size_t)(e * NOCT + ko) * DOUT + n4) * 8;
#pragma unroll
  for (int i = 0; i < 4; ++i) {
    ushort o8[8];
#pragma unroll
    for (int j = 0; j < 8; ++j) o8[j] = f2bf(v[j][i]);
    *(uint4*)(dst + i * 8) = *(const uint4*)o8;
  }
}

// ---- main GEMM: out[128x128 tile] = xp(128xK) @ Boct[e](Kx128), K=1088 ----
// BK=32, 4 waves, each 64x64 via 4x4 frags of 16x16x32 bf16 MFMA.
// All staging via global_load_lds width 16 (async, no VGPR round-trip).
__global__ __launch_bounds__(256) void k_gemm_bf16(
    const ushort* __restrict__ xp, const ushort* __restrict__ Boct,
    const int* __restrict__ tok_exp, float* __restrict__ out) {
  __shared__ ushort As[128 * 32];      // 8 KB, row-major [m][k]
  __shared__ ushort Bs[4 * 128 * 8];   // 8 KB, [oct][n][8]

  const int tid = threadIdx.x;
  const int lane = tid & 63;
  const int wave = tid >> 6;
  const int wm = wave >> 1, wn = wave & 1;

  const int row0 = blockIdx.y * 128;
  const int n0 = blockIdx.x * 128;
  const int e = tok_exp[row0];
  const ushort* boct = Boct + (size_t)e * NOCT * DOUT * 8;

  f32x4 acc[4][4];
#pragma unroll
  for (int mi = 0; mi < 4; ++mi)
#pragma unroll
    for (int ni = 0; ni < 4; ++ni) acc[mi][ni] = (f32x4){0.f, 0.f, 0.f, 0.f};

  for (int kt = 0; kt < KEXT / 32; ++kt) {
    // A: 8 KB = 4 waves x 2 calls x 1 KB
#pragma unroll
    for (int rd = 0; rd < 2; ++rd) {
      int row = wave * 32 + rd * 16 + (lane >> 2);
      const ushort* src = xp + (size_t)(row0 + row) * KEXT + kt * 32 + (lane & 3) * 8;
      gload_lds16(src, &As[wave * 1024 + rd * 512]);
    }
    // B: 8 KB = 4 waves (one oct each) x 2 calls x 1 KB, contiguous source
#pragma unroll
    for (int rd = 0; rd < 2; ++rd) {
      const ushort* src = boct + ((size_t)(kt * 4 + wave) * DOUT + n0 + rd * 64 + lane) * 8;
      gload_lds16(src, &Bs[wave * 1024 + rd * 512]);
    }
    __syncthreads();

    short8 af[4], bfv[4];
#pragma unroll
    for (int mi = 0; mi < 4; ++mi) {
      int m = wm * 64 + mi * 16 + (lane & 15);
      af[mi] = *(const short8*)&As[m * 32 + (lane >> 4) * 8];
    }
#pragma unroll
    for (int ni = 0; ni < 4; ++ni) {
      int n = wn * 64 + ni * 16 + (lane & 15);
      bfv[ni] = *(const short8*)&Bs[((lane >> 4) * 128 + n) * 8];
    }
#pragma unroll
    for (int mi = 0; mi < 4; ++mi)
#pragma unroll
      for (int ni = 0; ni < 4; ++ni)
        acc[mi][ni] = __builtin_amdgcn_mfma_f32_16x16x32_bf16(
            af[mi], bfv[ni], acc[mi][ni], 0, 0, 0);
    __syncthreads();
  }

  // epilogue: C layout col=lane&15, row=(lane>>4)*4+reg
#pragma unroll
  for (int mi = 0; mi < 4; ++mi) {
#pragma unroll
    for (int ni = 0; ni < 4; ++ni) {
      int col = n0 + wn * 64 + ni * 16 + (lane & 15);
#pragma unroll
      for (int i = 0; i < 4; ++i) {
        int row = row0 + wm * 64 + mi * 16 + (lane >> 4) * 4 + i;
        out[(size_t)row * DOUT + col] = acc[mi][ni][i];
      }
    }
  }
}

// ================= fallback path (round-2, needs only ~2.1 MB ws) =============
__global__ __launch_bounds__(256) void k_vprime_fb(
    const float* __restrict__ x, const float* __restrict__ lora_A,
    const float* __restrict__ lora_scaling, const int* __restrict__ adapter_idx,
    const int* __restrict__ tok_exp, float* __restrict__ vprime) {
  const int lane = threadIdx.x & 63;
  const int t = blockIdx.x * 4 + (threadIdx.x >> 6);
  const int a = adapter_idx[t];
  const int e = tok_exp[t];
  const float* abase = lora_A + (size_t)(a * NE + e) * DIN * RK;
  float acc[RK];
#pragma unroll
  for (int r = 0; r < RK; ++r) acc[r] = 0.f;
#pragma unroll
  for (int i = 0; i < 4; ++i) {
    int k = i * 256 + lane * 4;
    float4 xv = *(const float4*)(x + (size_t)t * DIN + k);
    const float xk[4] = {xv.x, xv.y, xv.z, xv.w};
#pragma unroll
    for (int d = 0; d < 4; ++d) {
      const float* ar = abase + (size_t)(k + d) * RK;
#pragma unroll
      for (int r = 0; r < RK; ++r) acc[r] += xk[d] * ar[r];
    }
  }
#pragma unroll
  for (int off = 1; off < 64; off <<= 1) {
#pragma unroll
    for (int r = 0; r < RK; ++r) acc[r] += __shfl_xor(acc[r], off, 64);
  }
  float s = lora_scaling[a];
  int c = lane;
  vprime[(size_t)t * 64 + c] = ((c >> 4) == a) ? s * acc[c & 15] : 0.f;
}

__global__ __launch_bounds__(256) void k_gemm_fb(
    const float* __restrict__ x, const float* __restrict__ weight,
    const float* __restrict__ lora_B, const float* __restrict__ vprime,
    const int* __restrict__ tok_exp, float* __restrict__ out) {
  __shared__ ushort As[128 * 32];
  __shared__ ushort Bs[4 * 128 * 8];
  const int tid = threadIdx.x;
  const int lane = tid & 63;
  const int wave = tid >> 6;
  const int wm = wave >> 1, wn = wave & 1;
  const int row0 = blockIdx.y * 128;
  const int n0 = blockIdx.x * 128;
  const int e = tok_exp[row0];
  const float* wbase = weight + (size_t)e * DIN * DOUT;
  f32x4 acc[4][4];
#pragma unroll
  for (int mi = 0; mi < 4; ++mi)
#pragma unroll
    for (int ni = 0; ni < 4; ++ni) acc[mi][ni] = (f32x4){0.f, 0.f, 0.f, 0.f};
  const int ko = wave, p = lane;
  for (int kt = 0; kt < 34; ++kt) {
    {
      const float* abase; int astride;
      if (kt < 32) { abase = x + (size_t)row0 * DIN + kt * 32; astride = DIN; }
      else         { abase = vprime + (size_t)row0 * 64 + (kt - 32) * 32; astride = 64; }
#pragma unroll
      for (int q = 0; q < 4; ++q) {
        int chunk = tid + q * 256;
        int row = chunk >> 3, c4 = chunk & 7;
        float4 v = *(const float4*)(abase + (size_t)row * astride + c4 * 4);
        ushort4 b;
        b.x = f2bf(v.x); b.y = f2bf(v.y); b.z = f2bf(v.z); b.w = f2bf(v.w);
        *(ushort4*)&As[row * 32 + c4 * 4] = b;
      }
    }
    {
      float2 d[8];
      if (kt < 32) {
        const float* bb = wbase + (size_t)(kt * 32 + ko * 8) * DOUT + n0 + 2 * p;
#pragma unroll
        for (int j = 0; j < 8; ++j) d[j] = *(const float2*)(bb + (size_t)j * DOUT);
      } else {
#pragma unroll
        for (int j = 0; j < 8; ++j) {
          int kv = (kt - 32) * 32 + ko * 8 + j;
          int a = kv >> 4, r = kv & 15;
          d[j] = *(const float2*)(lora_B + (size_t)((a * NE + e) * RK + r) * DOUT + n0 + 2 * p);
        }
      }
      uint32_t lo[4], hi[4];
#pragma unroll
      for (int j = 0; j < 4; ++j) {
        lo[j] = (uint32_t)f2bf(d[2 * j].x) | ((uint32_t)f2bf(d[2 * j + 1].x) << 16);
        hi[j] = (uint32_t)f2bf(d[2 * j].y) | ((uint32_t)f2bf(d[2 * j + 1].y) << 16);
      }
      *(uint4*)&Bs[ko * 1024 + p * 16]     = make_uint4(lo[0], lo[1], lo[2], lo[3]);
      *(uint4*)&Bs[ko * 1024 + p * 16 + 8] = make_uint4(hi[0], hi[1], hi[2], hi[3]);
    }
    __syncthreads();
    short8 af[4], bfv[4];
#pragma unroll
    for (int mi = 0; mi < 4; ++mi) {
      int m = wm * 64 + mi * 16 + (lane & 15);
      af[mi] = *(const short8*)&As[m * 32 + (lane >> 4) * 8];
    }
#pragma unroll
    for (int ni = 0; ni < 4; ++ni) {
      int n = wn * 64 + ni * 16 + (lane & 15);
      bfv[ni] = *(const short8*)&Bs[((lane >> 4) * 128 + n) * 8];
    }
#pragma unroll
    for (int mi = 0; mi < 4; ++mi)
#pragma unroll
      for (int ni = 0; ni < 4; ++ni)
        acc[mi][ni] = __builtin_amdgcn_mfma_f32_16x16x32_bf16(
            af[mi], bfv[ni], acc[mi][ni], 0, 0, 0);
    __syncthreads();
  }
#pragma unroll
  for (int mi = 0; mi < 4; ++mi)
#pragma unroll
    for (int ni = 0; ni < 4; ++ni) {
      int col = n0 + wn * 64 + ni * 16 + (lane & 15);
#pragma unroll
      for (int i = 0; i < 4; ++i) {
        int row = row0 + wm * 64 + mi * 16 + (lane >> 4) * 4 + i;
        out[(size_t)row * DOUT + col] = acc[mi][ni][i];
      }
    }
}

extern "C" void kernel_launch(void* const* d_in, const int* in_sizes, int n_in,
                              void* d_out, int out_size, void* d_ws, size_t ws_size,
                              hipStream_t stream) {
  const float* x            = (const float*)d_in[0];
  const float* weight       = (const float*)d_in[1];
  const float* lora_A       = (const float*)d_in[2];
  const float* lora_B       = (const float*)d_in[3];
  const float* lora_scaling = (const float*)d_in[4];
  const int*   group_sizes  = (const int*)d_in[5];
  const int*   adapter_idx  = (const int*)d_in[6];
  float* out = (float*)d_out;

  const size_t off_xp   = 32768;                                 // after tok_exp
  const size_t sz_xp    = (size_t)T_TOK * KEXT * 2;              // 17.8 MB
  const size_t off_boct = off_xp + sz_xp;
  const size_t sz_boct  = (size_t)NE * NOCT * DOUT * 8 * 2;      // 17.8 MB
  const size_t need     = off_boct + sz_boct;

  int* tok_exp = (int*)d_ws;
  k_token_expert<<<T_TOK / 256, 256, 0, stream>>>(group_sizes, tok_exp);

  if (ws_size >= need) {
    ushort* xp   = (ushort*)((char*)d_ws + off_xp);
    ushort* boct = (ushort*)((char*)d_ws + off_boct);
    k_pack_x<<<T_TOK / 4, 256, 0, stream>>>(x, lora_A, lora_scaling, adapter_idx,
                                            tok_exp, xp);
    dim3 gb(NOCT, NE);
    k_pack_B<<<gb, 256, 0, stream>>>(weight, lora_B, boct);
    dim3 grid(DOUT / 128, T_TOK / 128);
    k_gemm_bf16<<<grid, 256, 0, stream>>>(xp, boct, tok_exp, out);
  } else {
    float* vprime = (float*)((char*)d_ws + off_xp);
    k_vprime_fb<<<T_TOK / 4, 256, 0, stream>>>(x, lora_A, lora_scaling, adapter_idx,
                                               tok_exp, vprime);
    dim3 grid(DOUT / 128, T_TOK / 128);
    k_gemm_fb<<<grid, 256, 0, stream>>>(x, weight, lora_B, vprime, tok_exp, out);
  }
}

// Round 4
// 177.843 us; speedup vs baseline: 1.3652x; 1.3652x over previous
//
#include <hip/hip_runtime.h>
#include <hip/hip_bf16.h>
#include <stdint.h>

// LoRAExpert: out = ragged_dot(x, W, groups) + scale[a] * ((x @ A[a,e]) @ B[a,e])
// T=8192, D_IN=D_OUT=1024, E=8 (equal groups of 1024), A=4 adapters, R=16.
// Inputs fp32, output fp32 (confirmed round 2).
// Round 4: replace the 103us latency-bound fused pack_x with:
//   k_pack_x : pure fp32->bf16 convert of x into xp[:, 0:1024]
//   k_pack_A : Aoct[e][ko][c][8] bf16, scale[c>>4] folded into columns
//   k_vA     : MFMA GEMM V = xp @ Aoct[e], adapter-masked, -> xp[:, 1024:1088]
// Main GEMM (unchanged structure): out = xp(K=1088) @ Boct[e], async staging.

#define T_TOK 8192
#define DIN   1024
#define DOUT  1024
#define NE    8
#define NA    4
#define RK    16
#define KEXT  1088      // 1024 + NA*RK
#define NOCT  136       // KEXT/8

typedef __attribute__((ext_vector_type(8))) short short8;
typedef __attribute__((ext_vector_type(4))) float f32x4;

__device__ __forceinline__ ushort f2bf(float f) {
  union { float f; uint32_t i; } v; v.f = f;
  uint32_t x = v.i;
  return (ushort)((x + 0x7fffu + ((x >> 16) & 1u)) >> 16);  // RNE
}

__device__ __forceinline__ void gload_lds16(const void* g, void* l) {
  __builtin_amdgcn_global_load_lds(
      (const __attribute__((address_space(1))) uint32_t*)g,
      (__attribute__((address_space(3))) uint32_t*)l,
      16, 0, 0);
}

// ---- token -> expert map ----
__global__ void k_token_expert(const int* __restrict__ gs, int* __restrict__ tok_exp) {
  int t = blockIdx.x * blockDim.x + threadIdx.x;
  if (t >= T_TOK) return;
  int cum = 0, e = 0;
#pragma unroll
  for (int i = 0; i < NE; ++i) { if (t >= cum) e = i; cum += gs[i]; }
  tok_exp[t] = e;
}

// ---- pure convert: xp[t][0..1023] = bf16(x[t][:]) ----
__global__ __launch_bounds__(256) void k_pack_x(
    const float* __restrict__ x, ushort* __restrict__ xp) {
  int idx = blockIdx.x * 256 + threadIdx.x;      // one float4 per thread
  int row = idx >> 8;                             // DIN/4 = 256 chunks per row
  int c4 = idx & 255;
  float4 v = *(const float4*)(x + (size_t)row * DIN + c4 * 4);
  ushort4 b;
  b.x = f2bf(v.x); b.y = f2bf(v.y); b.z = f2bf(v.z); b.w = f2bf(v.w);
  *(ushort4*)(xp + (size_t)row * KEXT + c4 * 4) = b;
}

// ---- pack lora_A -> Aoct[e][ko 0..127][c 0..63][8] bf16, scale folded ----
__global__ __launch_bounds__(64) void k_pack_A(
    const float* __restrict__ lora_A, const float* __restrict__ lora_scaling,
    ushort* __restrict__ Aoct) {
  const int ko = blockIdx.x;        // 0..127
  const int e  = blockIdx.y;        // 0..7
  const int c  = threadIdx.x;       // 0..63
  const int a = c >> 4, r = c & 15;
  const float s = lora_scaling[a];
  ushort o8[8];
#pragma unroll
  for (int j = 0; j < 8; ++j) {
    int k = ko * 8 + j;
    float v = lora_A[((size_t)(a * NE + e) * DIN + k) * RK + r];
    o8[j] = f2bf(s * v);
  }
  *(uint4*)(Aoct + ((size_t)((e * 128 + ko) * 64 + c)) * 8) = *(const uint4*)o8;
}

// ---- pack W + lora_B -> oct-interleaved bf16 Boct[e][ko][n][8] ----
__global__ __launch_bounds__(256) void k_pack_B(
    const float* __restrict__ weight, const float* __restrict__ lora_B,
    ushort* __restrict__ Boct) {
  const int ko = blockIdx.x;         // 0..135
  const int e  = blockIdx.y;         // 0..7
  const int tid = threadIdx.x;
  const int n4 = tid * 4;

  float v[8][4];
  if (ko < 128) {
    const float* wb = weight + (size_t)e * DIN * DOUT + (size_t)(ko * 8) * DOUT + n4;
#pragma unroll
    for (int j = 0; j < 8; ++j) {
      float4 q = *(const float4*)(wb + (size_t)j * DOUT);
      v[j][0] = q.x; v[j][1] = q.y; v[j][2] = q.z; v[j][3] = q.w;
    }
  } else {
    int o = ko - 128;
#pragma unroll
    for (int j = 0; j < 8; ++j) {
      int kv = o * 8 + j;            // 0..63
      int a = kv >> 4, r = kv & 15;
      float4 q = *(const float4*)(lora_B + (size_t)((a * NE + e) * RK + r) * DOUT + n4);
      v[j][0] = q.x; v[j][1] = q.y; v[j][2] = q.z; v[j][3] = q.w;
    }
  }
  ushort* dst = Boct + ((size_t)(e * NOCT + ko) * DOUT + n4) * 8;
#pragma unroll
  for (int i = 0; i < 4; ++i) {
    ushort o8[8];
#pragma unroll
    for (int j = 0; j < 8; ++j) o8[j] = f2bf(v[j][i]);
    *(uint4*)(dst + i * 8) = *(const uint4*)o8;
  }
}

// ---- V = xp[:, :1024] @ Aoct[e]  (MFMA), masked -> xp[:, 1024:1088] ----
// block = 256 thr = 4 waves, 64 rows x 64 cols; wave w: rows w*16..w*16+15.
__global__ __launch_bounds__(256) void k_vA(
    ushort* __restrict__ xp, const ushort* __restrict__ Aoct,
    const int* __restrict__ tok_exp, const int* __restrict__ adapter_idx) {
  __shared__ ushort As2[64 * 32];     // 4 KB
  __shared__ ushort Bs2[4 * 64 * 8];  // 4 KB

  const int tid = threadIdx.x;
  const int lane = tid & 63;
  const int wave = tid >> 6;
  const int rows0 = blockIdx.x * 64;
  const int e = tok_exp[rows0];
  const ushort* aoct = Aoct + (size_t)e * 128 * 64 * 8;

  f32x4 acc[4];
#pragma unroll
  for (int ni = 0; ni < 4; ++ni) acc[ni] = (f32x4){0.f, 0.f, 0.f, 0.f};

  for (int kt = 0; kt < 32; ++kt) {
    {
      int row = wave * 16 + (lane >> 2);
      const ushort* src = xp + (size_t)(rows0 + row) * KEXT + kt * 32 + (lane & 3) * 8;
      gload_lds16(src, &As2[wave * 512]);
    }
    {
      const ushort* src = aoct + ((size_t)(kt * 4 + wave) * 64 + lane) * 8;
      gload_lds16(src, &Bs2[wave * 512]);
    }
    __syncthreads();

    short8 af = *(const short8*)&As2[(wave * 16 + (lane & 15)) * 32 + (lane >> 4) * 8];
#pragma unroll
    for (int ni = 0; ni < 4; ++ni) {
      short8 bfv = *(const short8*)&Bs2[((lane >> 4) * 64 + ni * 16 + (lane & 15)) * 8];
      acc[ni] = __builtin_amdgcn_mfma_f32_16x16x32_bf16(af, bfv, acc[ni], 0, 0, 0);
    }
    __syncthreads();
  }

  // epilogue: col = ni*16 + (lane&15) -> adapter slot is exactly ni.
#pragma unroll
  for (int i = 0; i < 4; ++i) {
    int grow = rows0 + wave * 16 + (lane >> 4) * 4 + i;
    int a_row = adapter_idx[grow];
#pragma unroll
    for (int ni = 0; ni < 4; ++ni) {
      float val = (a_row == ni) ? acc[ni][i] : 0.f;
      xp[(size_t)grow * KEXT + DIN + ni * 16 + (lane & 15)] = f2bf(val);
    }
  }
}

// ---- main GEMM: out[128x128 tile] = xp(128xK) @ Boct[e](Kx128), K=1088 ----
__global__ __launch_bounds__(256) void k_gemm_bf16(
    const ushort* __restrict__ xp, const ushort* __restrict__ Boct,
    const int* __restrict__ tok_exp, float* __restrict__ out) {
  __shared__ ushort As[128 * 32];      // 8 KB
  __shared__ ushort Bs[4 * 128 * 8];   // 8 KB

  const int tid = threadIdx.x;
  const int lane = tid & 63;
  const int wave = tid >> 6;
  const int wm = wave >> 1, wn = wave & 1;

  const int row0 = blockIdx.y * 128;
  const int n0 = blockIdx.x * 128;
  const int e = tok_exp[row0];
  const ushort* boct = Boct + (size_t)e * NOCT * DOUT * 8;

  f32x4 acc[4][4];
#pragma unroll
  for (int mi = 0; mi < 4; ++mi)
#pragma unroll
    for (int ni = 0; ni < 4; ++ni) acc[mi][ni] = (f32x4){0.f, 0.f, 0.f, 0.f};

  for (int kt = 0; kt < KEXT / 32; ++kt) {
#pragma unroll
    for (int rd = 0; rd < 2; ++rd) {
      int row = wave * 32 + rd * 16 + (lane >> 2);
      const ushort* src = xp + (size_t)(row0 + row) * KEXT + kt * 32 + (lane & 3) * 8;
      gload_lds16(src, &As[wave * 1024 + rd * 512]);
    }
#pragma unroll
    for (int rd = 0; rd < 2; ++rd) {
      const ushort* src = boct + ((size_t)(kt * 4 + wave) * DOUT + n0 + rd * 64 + lane) * 8;
      gload_lds16(src, &Bs[wave * 1024 + rd * 512]);
    }
    __syncthreads();

    short8 af[4], bfv[4];
#pragma unroll
    for (int mi = 0; mi < 4; ++mi) {
      int m = wm * 64 + mi * 16 + (lane & 15);
      af[mi] = *(const short8*)&As[m * 32 + (lane >> 4) * 8];
    }
#pragma unroll
    for (int ni = 0; ni < 4; ++ni) {
      int n = wn * 64 + ni * 16 + (lane & 15);
      bfv[ni] = *(const short8*)&Bs[((lane >> 4) * 128 + n) * 8];
    }
#pragma unroll
    for (int mi = 0; mi < 4; ++mi)
#pragma unroll
      for (int ni = 0; ni < 4; ++ni)
        acc[mi][ni] = __builtin_amdgcn_mfma_f32_16x16x32_bf16(
            af[mi], bfv[ni], acc[mi][ni], 0, 0, 0);
    __syncthreads();
  }

#pragma unroll
  for (int mi = 0; mi < 4; ++mi) {
#pragma unroll
    for (int ni = 0; ni < 4; ++ni) {
      int col = n0 + wn * 64 + ni * 16 + (lane & 15);
#pragma unroll
      for (int i = 0; i < 4; ++i) {
        int row = row0 + wm * 64 + mi * 16 + (lane >> 4) * 4 + i;
        out[(size_t)row * DOUT + col] = acc[mi][ni][i];
      }
    }
  }
}

// ================= fallback path (round-2, needs only ~2.1 MB ws) =============
__global__ __launch_bounds__(256) void k_vprime_fb(
    const float* __restrict__ x, const float* __restrict__ lora_A,
    const float* __restrict__ lora_scaling, const int* __restrict__ adapter_idx,
    const int* __restrict__ tok_exp, float* __restrict__ vprime) {
  const int lane = threadIdx.x & 63;
  const int t = blockIdx.x * 4 + (threadIdx.x >> 6);
  const int a = adapter_idx[t];
  const int e = tok_exp[t];
  const float* abase = lora_A + (size_t)(a * NE + e) * DIN * RK;
  float acc[RK];
#pragma unroll
  for (int r = 0; r < RK; ++r) acc[r] = 0.f;
#pragma unroll
  for (int i = 0; i < 4; ++i) {
    int k = i * 256 + lane * 4;
    float4 xv = *(const float4*)(x + (size_t)t * DIN + k);
    const float xk[4] = {xv.x, xv.y, xv.z, xv.w};
#pragma unroll
    for (int d = 0; d < 4; ++d) {
      const float* ar = abase + (size_t)(k + d) * RK;
#pragma unroll
      for (int r = 0; r < RK; ++r) acc[r] += xk[d] * ar[r];
    }
  }
#pragma unroll
  for (int off = 1; off < 64; off <<= 1) {
#pragma unroll
    for (int r = 0; r < RK; ++r) acc[r] += __shfl_xor(acc[r], off, 64);
  }
  float s = lora_scaling[a];
  int c = lane;
  vprime[(size_t)t * 64 + c] = ((c >> 4) == a) ? s * acc[c & 15] : 0.f;
}

__global__ __launch_bounds__(256) void k_gemm_fb(
    const float* __restrict__ x, const float* __restrict__ weight,
    const float* __restrict__ lora_B, const float* __restrict__ vprime,
    const int* __restrict__ tok_exp, float* __restrict__ out) {
  __shared__ ushort As[128 * 32];
  __shared__ ushort Bs[4 * 128 * 8];
  const int tid = threadIdx.x;
  const int lane = tid & 63;
  const int wave = tid >> 6;
  const int wm = wave >> 1, wn = wave & 1;
  const int row0 = blockIdx.y * 128;
  const int n0 = blockIdx.x * 128;
  const int e = tok_exp[row0];
  const float* wbase = weight + (size_t)e * DIN * DOUT;
  f32x4 acc[4][4];
#pragma unroll
  for (int mi = 0; mi < 4; ++mi)
#pragma unroll
    for (int ni = 0; ni < 4; ++ni) acc[mi][ni] = (f32x4){0.f, 0.f, 0.f, 0.f};
  const int ko = wave, p = lane;
  for (int kt = 0; kt < 34; ++kt) {
    {
      const float* abase; int astride;
      if (kt < 32) { abase = x + (size_t)row0 * DIN + kt * 32; astride = DIN; }
      else         { abase = vprime + (size_t)row0 * 64 + (kt - 32) * 32; astride = 64; }
#pragma unroll
      for (int q = 0; q < 4; ++q) {
        int chunk = tid + q * 256;
        int row = chunk >> 3, c4 = chunk & 7;
        float4 v = *(const float4*)(abase + (size_t)row * astride + c4 * 4);
        ushort4 b;
        b.x = f2bf(v.x); b.y = f2bf(v.y); b.z = f2bf(v.z); b.w = f2bf(v.w);
        *(ushort4*)&As[row * 32 + c4 * 4] = b;
      }
    }
    {
      float2 d[8];
      if (kt < 32) {
        const float* bb = wbase + (size_t)(kt * 32 + ko * 8) * DOUT + n0 + 2 * p;
#pragma unroll
        for (int j = 0; j < 8; ++j) d[j] = *(const float2*)(bb + (size_t)j * DOUT);
      } else {
#pragma unroll
        for (int j = 0; j < 8; ++j) {
          int kv = (kt - 32) * 32 + ko * 8 + j;
          int a = kv >> 4, r = kv & 15;
          d[j] = *(const float2*)(lora_B + (size_t)((a * NE + e) * RK + r) * DOUT + n0 + 2 * p);
        }
      }
      uint32_t lo[4], hi[4];
#pragma unroll
      for (int j = 0; j < 4; ++j) {
        lo[j] = (uint32_t)f2bf(d[2 * j].x) | ((uint32_t)f2bf(d[2 * j + 1].x) << 16);
        hi[j] = (uint32_t)f2bf(d[2 * j].y) | ((uint32_t)f2bf(d[2 * j + 1].y) << 16);
      }
      *(uint4*)&Bs[ko * 1024 + p * 16]     = make_uint4(lo[0], lo[1], lo[2], lo[3]);
      *(uint4*)&Bs[ko * 1024 + p * 16 + 8] = make_uint4(hi[0], hi[1], hi[2], hi[3]);
    }
    __syncthreads();
    short8 af[4], bfv[4];
#pragma unroll
    for (int mi = 0; mi < 4; ++mi) {
      int m = wm * 64 + mi * 16 + (lane & 15);
      af[mi] = *(const short8*)&As[m * 32 + (lane >> 4) * 8];
    }
#pragma unroll
    for (int ni = 0; ni < 4; ++ni) {
      int n = wn * 64 + ni * 16 + (lane & 15);
      bfv[ni] = *(const short8*)&Bs[((lane >> 4) * 128 + n) * 8];
    }
#pragma unroll
    for (int mi = 0; mi < 4; ++mi)
#pragma unroll
      for (int ni = 0; ni < 4; ++ni)
        acc[mi][ni] = __builtin_amdgcn_mfma_f32_16x16x32_bf16(
            af[mi], bfv[ni], acc[mi][ni], 0, 0, 0);
    __syncthreads();
  }
#pragma unroll
  for (int mi = 0; mi < 4; ++mi)
#pragma unroll
    for (int ni = 0; ni < 4; ++ni) {
      int col = n0 + wn * 64 + ni * 16 + (lane & 15);
#pragma unroll
      for (int i = 0; i < 4; ++i) {
        int row = row0 + wm * 64 + mi * 16 + (lane >> 4) * 4 + i;
        out[(size_t)row * DOUT + col] = acc[mi][ni][i];
      }
    }
}

extern "C" void kernel_launch(void* const* d_in, const int* in_sizes, int n_in,
                              void* d_out, int out_size, void* d_ws, size_t ws_size,
                              hipStream_t stream) {
  const float* x            = (const float*)d_in[0];
  const float* weight       = (const float*)d_in[1];
  const float* lora_A       = (const float*)d_in[2];
  const float* lora_B       = (const float*)d_in[3];
  const float* lora_scaling = (const float*)d_in[4];
  const int*   group_sizes  = (const int*)d_in[5];
  const int*   adapter_idx  = (const int*)d_in[6];
  float* out = (float*)d_out;

  const size_t off_xp   = 32768;
  const size_t sz_xp    = (size_t)T_TOK * KEXT * 2;              // 17.8 MB
  const size_t off_boct = off_xp + sz_xp;
  const size_t sz_boct  = (size_t)NE * NOCT * DOUT * 8 * 2;      // 17.8 MB
  const size_t off_aoct = off_boct + sz_boct;
  const size_t sz_aoct  = (size_t)NE * 128 * 64 * 8 * 2;         // 1 MB
  const size_t need     = off_aoct + sz_aoct;

  int* tok_exp = (int*)d_ws;
  k_token_expert<<<T_TOK / 256, 256, 0, stream>>>(group_sizes, tok_exp);

  if (ws_size >= need) {
    ushort* xp   = (ushort*)((char*)d_ws + off_xp);
    ushort* boct = (ushort*)((char*)d_ws + off_boct);
    ushort* aoct = (ushort*)((char*)d_ws + off_aoct);
    k_pack_x<<<(T_TOK * DIN / 4) / 256, 256, 0, stream>>>(x, xp);
    dim3 ga(128, NE);
    k_pack_A<<<ga, 64, 0, stream>>>(lora_A, lora_scaling, aoct);
    dim3 gb(NOCT, NE);
    k_pack_B<<<gb, 256, 0, stream>>>(weight, lora_B, boct);
    k_vA<<<T_TOK / 64, 256, 0, stream>>>(xp, aoct, tok_exp, adapter_idx);
    dim3 grid(DOUT / 128, T_TOK / 128);
    k_gemm_bf16<<<grid, 256, 0, stream>>>(xp, boct, tok_exp, out);
  } else {
    float* vprime = (float*)((char*)d_ws + off_xp);
    k_vprime_fb<<<T_TOK / 4, 256, 0, stream>>>(x, lora_A, lora_scaling, adapter_idx,
                                               tok_exp, vprime);
    dim3 grid(DOUT / 128, T_TOK / 128);
    k_gemm_fb<<<grid, 256, 0, stream>>>(x, weight, lora_B, vprime, tok_exp, out);
  }
}

// Round 5
// 165.515 us; speedup vs baseline: 1.4669x; 1.0745x over previous
//
#include <hip/hip_runtime.h>
#include <hip/hip_bf16.h>
#include <stdint.h>

// LoRAExpert: out = ragged_dot(x, W, groups) + scale[a] * ((x @ A[a,e]) @ B[a,e])
// T=8192, D_IN=D_OUT=1024, E=8 (equal groups of 1024), A=4 adapters, R=16.
// Inputs fp32, output fp32 (confirmed round 2). ws = 256 MiB (confirmed round 4).
//
// Round 5: 3 kernels (was 6):
//   k_prep : pack x->bf16 xp[:, :1024]; lora_A -> Aoct (scale folded);
//            W/lora_B -> Boct oct-interleaved. One launch, grid ranges.
//   k_vA   : V = xp @ Aoct[e] (MFMA, BK=64, swizzled A LDS), adapter-masked
//            -> xp[:, 1024:1088]. Expert id computed inline from group_sizes.
//   k_gemm : out = xp(K=1088) @ Boct[e], BK=64 (17 iters), XOR-swizzled A tile
//            (kills the 16-way bank conflict 128B-row layout would have),
//            all staging via global_load_lds width 16.

#define T_TOK 8192
#define DIN   1024
#define DOUT  1024
#define NE    8
#define NA    4
#define RK    16
#define KEXT  1088      // 1024 + NA*RK
#define NOCT  136       // KEXT/8

typedef __attribute__((ext_vector_type(8))) short short8;
typedef __attribute__((ext_vector_type(4))) float f32x4;

__device__ __forceinline__ ushort f2bf(float f) {
  union { float f; uint32_t i; } v; v.f = f;
  uint32_t x = v.i;
  return (ushort)((x + 0x7fffu + ((x >> 16) & 1u)) >> 16);  // RNE
}

__device__ __forceinline__ void gload_lds16(const void* g, void* l) {
  __builtin_amdgcn_global_load_lds(
      (const __attribute__((address_space(1))) uint32_t*)g,
      (__attribute__((address_space(3))) uint32_t*)l,
      16, 0, 0);
}

__device__ __forceinline__ int expert_of_row(const int* __restrict__ gs, int row) {
  int cum = 0, e = 0;
#pragma unroll
  for (int i = 0; i < NE; ++i) { if (row >= cum) e = i; cum += gs[i]; }
  return e;
}

// ---- k_prep: all packing in one launch ----
// blocks [0, 8192)          : x -> bf16 xp[:, :1024]
// blocks [8192, 8448)       : lora_A -> Aoct[e][ko][c][8], scale folded
// blocks [8448, 9472)       : W -> Boct[e][ko<128][n][8]
// blocks [9472, 9536)       : lora_B -> Boct[e][128+o][n][8]
__global__ __launch_bounds__(256) void k_prep(
    const float* __restrict__ x, const float* __restrict__ weight,
    const float* __restrict__ lora_A, const float* __restrict__ lora_B,
    const float* __restrict__ lora_scaling,
    ushort* __restrict__ xp, ushort* __restrict__ Aoct, ushort* __restrict__ Boct) {
  const int bid = blockIdx.x;
  const int tid = threadIdx.x;

  if (bid < 8192) {                       // ---- pack x ----
    int idx = bid * 256 + tid;            // one float4 per thread
    int row = idx >> 8;                   // 256 float4 per row
    int c4 = idx & 255;
    float4 v = *(const float4*)(x + (size_t)row * DIN + c4 * 4);
    ushort4 b;
    b.x = f2bf(v.x); b.y = f2bf(v.y); b.z = f2bf(v.z); b.w = f2bf(v.w);
    *(ushort4*)(xp + (size_t)row * KEXT + c4 * 4) = b;
  } else if (bid < 8448) {                // ---- pack lora_A ----
    int u = (bid - 8192) * 4 + (tid >> 6);  // 0..1023 = e*128+ko
    int e = u >> 7, ko = u & 127;
    int c = tid & 63;
    int a = c >> 4, r = c & 15;
    float s = lora_scaling[a];
    ushort o8[8];
#pragma unroll
    for (int j = 0; j < 8; ++j) {
      float v = lora_A[((size_t)(a * NE + e) * DIN + ko * 8 + j) * RK + r];
      o8[j] = f2bf(s * v);
    }
    *(uint4*)(Aoct + ((size_t)((e * 128 + ko) * 64 + c)) * 8) = *(const uint4*)o8;
  } else {                                // ---- pack Boct ----
    int e, ko;
    const float* srcbase;
    int stride;
    if (bid < 9472) {                     // W rows
      int u = bid - 8448;                 // 0..1023
      e = u >> 7; ko = u & 127;
      srcbase = weight + (size_t)e * DIN * DOUT + (size_t)(ko * 8) * DOUT;
      stride = DOUT;
    } else {                              // lora_B rows
      int u = bid - 9472;                 // 0..63
      e = u >> 3; int o = u & 7; ko = 128 + o;
      // kv = o*8 + j : a = kv>>4, r = kv&15 -> rows are contiguous in lora_B
      // lora_B[((a*NE+e)*RK + r)*DOUT + n]; for j=0..7 a,r vary. Handle per-j below.
      srcbase = nullptr; stride = 0;
    }
    int n4 = tid * 4;
    float v[8][4];
    if (bid < 9472) {
#pragma unroll
      for (int j = 0; j < 8; ++j) {
        float4 q = *(const float4*)(srcbase + (size_t)j * stride + n4);
        v[j][0] = q.x; v[j][1] = q.y; v[j][2] = q.z; v[j][3] = q.w;
      }
    } else {
      int o = ko - 128;
#pragma unroll
      for (int j = 0; j < 8; ++j) {
        int kv = o * 8 + j;
        int a = kv >> 4, r = kv & 15;
        float4 q = *(const float4*)(lora_B + (size_t)((a * NE + e) * RK + r) * DOUT + n4);
        v[j][0] = q.x; v[j][1] = q.y; v[j][2] = q.z; v[j][3] = q.w;
      }
    }
    ushort* dst = Boct + ((size_t)(e * NOCT + ko) * DOUT + n4) * 8;
#pragma unroll
    for (int i = 0; i < 4; ++i) {
      ushort o8[8];
#pragma unroll
      for (int j = 0; j < 8; ++j) o8[j] = f2bf(v[j][i]);
      *(uint4*)(dst + i * 8) = *(const uint4*)o8;
    }
  }
}

// ---- k_vA: V = xp[:, :1024] @ Aoct[e], masked -> xp[:, 1024:1088] ----
// 128 blocks x 256 thr; tile 64 rows x 64 cols; BK=64 (16 iters).
// A LDS XOR-swizzled: chunk' = chunk ^ (row&7).
__global__ __launch_bounds__(256) void k_vA(
    ushort* __restrict__ xp, const ushort* __restrict__ Aoct,
    const int* __restrict__ gs, const int* __restrict__ adapter_idx) {
  __shared__ ushort As2[64 * 64];     // 8 KB
  __shared__ ushort Bs2[8 * 64 * 8];  // 8 KB

  const int tid = threadIdx.x;
  const int lane = tid & 63;
  const int wave = tid >> 6;
  const int rows0 = blockIdx.x * 64;
  const int e = expert_of_row(gs, rows0);
  const ushort* aoct = Aoct + (size_t)e * 128 * 64 * 8;

  f32x4 acc[4];
#pragma unroll
  for (int ni = 0; ni < 4; ++ni) acc[ni] = (f32x4){0.f, 0.f, 0.f, 0.f};

  const int r8 = lane >> 3;                     // row-within-call 0..7
  const int c8s = (lane & 7) ^ r8;              // swizzled source chunk

  for (int kt = 0; kt < 16; ++kt) {
    // A: 2 calls/wave, 8 rows x 8 chunks each, swizzled source
#pragma unroll
    for (int rd = 0; rd < 2; ++rd) {
      int row = wave * 16 + rd * 8 + r8;
      const ushort* src = xp + (size_t)(rows0 + row) * KEXT + kt * 64 + c8s * 8;
      gload_lds16(src, &As2[(wave * 16 + rd * 8) * 64]);
    }
    // B: 2 calls/wave, one oct each, contiguous
#pragma unroll
    for (int rd = 0; rd < 2; ++rd) {
      int o = wave * 2 + rd;                    // local oct 0..7
      const ushort* src = aoct + ((size_t)(kt * 8 + o) * 64 + lane) * 8;
      gload_lds16(src, &Bs2[o * 64 * 8]);
    }
    __syncthreads();

    int m = wave * 16 + (lane & 15);
#pragma unroll
    for (int h = 0; h < 2; ++h) {
      int kblk = h * 4 + (lane >> 4);
      short8 af = *(const short8*)&As2[m * 64 + (kblk ^ (m & 7)) * 8];
#pragma unroll
      for (int ni = 0; ni < 4; ++ni) {
        short8 bfv = *(const short8*)&Bs2[(kblk * 64 + ni * 16 + (lane & 15)) * 8];
        acc[ni] = __builtin_amdgcn_mfma_f32_16x16x32_bf16(af, bfv, acc[ni], 0, 0, 0);
      }
    }
    __syncthreads();
  }

  // epilogue: col = ni*16+(lane&15) -> adapter slot is ni
#pragma unroll
  for (int i = 0; i < 4; ++i) {
    int grow = rows0 + wave * 16 + (lane >> 4) * 4 + i;
    int a_row = adapter_idx[grow];
#pragma unroll
    for (int ni = 0; ni < 4; ++ni) {
      float val = (a_row == ni) ? acc[ni][i] : 0.f;
      xp[(size_t)grow * KEXT + DIN + ni * 16 + (lane & 15)] = f2bf(val);
    }
  }
}

// ---- k_gemm: out[128x128] = xp(128 x 1088) @ Boct[e](1088 x 128) ----
// BK=64, 17 iters. A LDS XOR-swizzled (conflict-free frag reads).
__global__ __launch_bounds__(256) void k_gemm(
    const ushort* __restrict__ xp, const ushort* __restrict__ Boct,
    const int* __restrict__ gs, float* __restrict__ out) {
  __shared__ ushort As[128 * 64];      // 16 KB
  __shared__ ushort Bs[8 * 128 * 8];   // 16 KB

  const int tid = threadIdx.x;
  const int lane = tid & 63;
  const int wave = tid >> 6;
  const int wm = wave >> 1, wn = wave & 1;

  const int row0 = blockIdx.y * 128;
  const int n0 = blockIdx.x * 128;
  const int e = expert_of_row(gs, row0);
  const ushort* boct = Boct + (size_t)e * NOCT * DOUT * 8;

  f32x4 acc[4][4];
#pragma unroll
  for (int mi = 0; mi < 4; ++mi)
#pragma unroll
    for (int ni = 0; ni < 4; ++ni) acc[mi][ni] = (f32x4){0.f, 0.f, 0.f, 0.f};

  const int r8 = lane >> 3;
  const int c8s = (lane & 7) ^ r8;              // swizzled source chunk

  for (int kt = 0; kt < 17; ++kt) {
    // A: 4 calls/wave, 8 rows x 8 chunks each (swizzled)
#pragma unroll
    for (int rd = 0; rd < 4; ++rd) {
      int row = wave * 32 + rd * 8 + r8;
      const ushort* src = xp + (size_t)(row0 + row) * KEXT + kt * 64 + c8s * 8;
      gload_lds16(src, &As[(wave * 32 + rd * 8) * 64]);
    }
    // B: 4 calls/wave: unit = wave*4+rd -> oct o=unit>>1, half hf=unit&1
#pragma unroll
    for (int rd = 0; rd < 4; ++rd) {
      int u = wave * 4 + rd;
      int o = u >> 1, hf = u & 1;
      const ushort* src = boct + ((size_t)(kt * 8 + o) * DOUT + n0 + hf * 64 + lane) * 8;
      gload_lds16(src, &Bs[(o * 128 + hf * 64) * 8]);
    }
    __syncthreads();

#pragma unroll
    for (int h = 0; h < 2; ++h) {
      int kblk = h * 4 + (lane >> 4);
      short8 af[4], bfv[4];
#pragma unroll
      for (int mi = 0; mi < 4; ++mi) {
        int m = wm * 64 + mi * 16 + (lane & 15);
        af[mi] = *(const short8*)&As[m * 64 + (kblk ^ (m & 7)) * 8];
      }
#pragma unroll
      for (int ni = 0; ni < 4; ++ni) {
        int n = wn * 64 + ni * 16 + (lane & 15);
        bfv[ni] = *(const short8*)&Bs[(kblk * 128 + n) * 8];
      }
#pragma unroll
      for (int mi = 0; mi < 4; ++mi)
#pragma unroll
        for (int ni = 0; ni < 4; ++ni)
          acc[mi][ni] = __builtin_amdgcn_mfma_f32_16x16x32_bf16(
              af[mi], bfv[ni], acc[mi][ni], 0, 0, 0);
    }
    __syncthreads();
  }

  // epilogue: C layout col=lane&15, row=(lane>>4)*4+reg
#pragma unroll
  for (int mi = 0; mi < 4; ++mi) {
#pragma unroll
    for (int ni = 0; ni < 4; ++ni) {
      int col = n0 + wn * 64 + ni * 16 + (lane & 15);
#pragma unroll
      for (int i = 0; i < 4; ++i) {
        int row = row0 + wm * 64 + mi * 16 + (lane >> 4) * 4 + i;
        out[(size_t)row * DOUT + col] = acc[mi][ni][i];
      }
    }
  }
}

extern "C" void kernel_launch(void* const* d_in, const int* in_sizes, int n_in,
                              void* d_out, int out_size, void* d_ws, size_t ws_size,
                              hipStream_t stream) {
  const float* x            = (const float*)d_in[0];
  const float* weight       = (const float*)d_in[1];
  const float* lora_A       = (const float*)d_in[2];
  const float* lora_B       = (const float*)d_in[3];
  const float* lora_scaling = (const float*)d_in[4];
  const int*   group_sizes  = (const int*)d_in[5];
  const int*   adapter_idx  = (const int*)d_in[6];
  float* out = (float*)d_out;

  const size_t sz_xp    = (size_t)T_TOK * KEXT * 2;              // 17.8 MB
  const size_t sz_boct  = (size_t)NE * NOCT * DOUT * 8 * 2;      // 17.8 MB
  ushort* xp   = (ushort*)d_ws;
  ushort* boct = (ushort*)((char*)d_ws + sz_xp);
  ushort* aoct = (ushort*)((char*)d_ws + sz_xp + sz_boct);       // 1 MB

  k_prep<<<9536, 256, 0, stream>>>(x, weight, lora_A, lora_B, lora_scaling,
                                   xp, aoct, boct);
  k_vA<<<T_TOK / 64, 256, 0, stream>>>(xp, aoct, group_sizes, adapter_idx);
  dim3 grid(DOUT / 128, T_TOK / 128);
  k_gemm<<<grid, 256, 0, stream>>>(xp, boct, group_sizes, out);
}